// Round 1
// baseline (89.865 us; speedup 1.0000x reference)
//
#include <hip/hip_runtime.h>

constexpr int K   = 49;   // 7x7 kernel flattened
constexpr int C   = 32;   // out channels
constexpr int BLK = 256;  // threads per block = windows per block

__global__ __launch_bounds__(BLK) void conv2d_im2col_kernel(
    const float* __restrict__ enc_x,
    const float* __restrict__ weight,   // [C*K], wave-uniform reads -> s_load
    const float* __restrict__ bias,     // [C]
    float* __restrict__ out,            // [C * windows_nb]
    int windows_nb)
{
    __shared__ float xs[BLK * K];       // 50176 B -> 3 blocks/CU (LDS-limited)

    const int t = threadIdx.x;
    const long long block_base = (long long)blockIdx.x * BLK;   // first window of block

    // ---- Stage 256 rows (12544 floats, 16B-aligned) global -> LDS, coalesced float4 ----
    const float4* __restrict__ src4 =
        reinterpret_cast<const float4*>(enc_x + block_base * K);
    float4* dst4 = reinterpret_cast<float4*>(xs);
    // 12544/4 = 3136 float4 = 12*256 + 64
    #pragma unroll
    for (int r = 0; r < 12; ++r)
        dst4[r * BLK + t] = src4[r * BLK + t];
    if (t < 64)
        dst4[12 * BLK + t] = src4[12 * BLK + t];

    __syncthreads();

    // ---- Each thread owns one window: pull its 49 inputs into registers ----
    // LDS pattern xs[t*49 + k]: stride 49 (odd) -> gcd(49,32)=1 -> 2 lanes/bank (free)
    float x[K];
    #pragma unroll
    for (int k = 0; k < K; ++k) x[k] = xs[t * K + k];

    const long long w = block_base + t;

    // ---- 32 channels; weights via uniform index -> SGPRs; 4-way partial sums ----
    for (int c = 0; c < C; ++c) {
        const float* wc = weight + c * K;
        float a0 = 0.f, a1 = 0.f, a2 = 0.f, a3 = 0.f;
        #pragma unroll
        for (int k = 0; k < K; k += 4) {
            a0 = fmaf(x[k], wc[k], a0);
            if (k + 1 < K) a1 = fmaf(x[k + 1], wc[k + 1], a1);
            if (k + 2 < K) a2 = fmaf(x[k + 2], wc[k + 2], a2);
            if (k + 3 < K) a3 = fmaf(x[k + 3], wc[k + 3], a3);
        }
        out[(long long)c * windows_nb + w] = (a0 + a1) + (a2 + a3) + bias[c];
    }
}

extern "C" void kernel_launch(void* const* d_in, const int* in_sizes, int n_in,
                              void* d_out, int out_size, void* d_ws, size_t ws_size,
                              hipStream_t stream) {
    const float* enc_x  = (const float*)d_in[0];
    const float* weight = (const float*)d_in[1];   // [C,7,7] flat = [C*K]
    const float* bias   = (const float*)d_in[2];   // [C]
    float* out = (float*)d_out;

    const int windows_nb = in_sizes[0] / K;        // 1048576
    const int nblocks = windows_nb / BLK;          // 4096 (exact for 1048576)

    conv2d_im2col_kernel<<<nblocks, BLK, 0, stream>>>(enc_x, weight, bias, out, windows_nb);
}